// Round 2
// baseline (108.401 us; speedup 1.0000x reference)
//
#include <hip/hip_runtime.h>

// Problem constants
#define H_ 96
#define W_ 96
#define HW 9216        // 96*96
#define C_ 64
#define OUTC 64
#define NPTS 9
#define NCH 18
#define B_ 8

// LDS patch: 8 rows x 24 cols x 64 ch (padded to 72 shorts) per 4-row x 16-col tile
#define PW  24
#define PCH 72

typedef __attribute__((ext_vector_type(8))) short short8;   // 8 bf16
typedef __attribute__((ext_vector_type(4))) float f32x4;
typedef __attribute__((ext_vector_type(4))) unsigned int uint4v;
typedef __attribute__((ext_vector_type(2))) unsigned int uint2v;

__device__ __forceinline__ short f2bf(float f) {
    union { float f; unsigned u; } v; v.f = f;
    unsigned r = v.u + 0x7fffu + ((v.u >> 16) & 1u);   // RNE
    return (short)(r >> 16);
}
__device__ __forceinline__ unsigned pk2bf(float lo, float hi) {
    return ((unsigned)(unsigned short)f2bf(hi) << 16) | (unsigned short)f2bf(lo);
}
__device__ __forceinline__ float bflo(unsigned d) {
    union { unsigned u; float f; } v; v.u = d << 16; return v.f;
}
__device__ __forceinline__ float bfhi(unsigned d) {
    union { unsigned u; float f; } v; v.u = d & 0xffff0000u; return v.f;
}

// ---------------- Kernel 1: weight-fragment prep only (x transpose eliminated) ----------------
__global__ __launch_bounds__(256) void prep_w(
    const float* __restrict__ w_ker, const float* __restrict__ w_off,
    short* __restrict__ wk_frag, short* __restrict__ woff_frag)
{
    int idx = blockIdx.x * 256 + threadIdx.x;       // 0..55295
    if (idx < 36864) {                              // wk_frag: NT=4
        int j = idx & 7, l = (idx >> 3) & 63, nt = (idx >> 9) & 3, sg = idx >> 11;
        int q2 = sg & 1, n = sg >> 1;
        int c  = q2 * 32 + ((l >> 4) << 3) + j;
        int oc = nt * 16 + (l & 15);
        wk_frag[idx] = f2bf(w_ker[(oc * C_ + c) * 9 + n]);
    } else {                                        // woff_frag: NT=2 (18 padded to 32)
        int k = idx - 36864;                        // 0..18431
        int j = k & 7, l = (k >> 3) & 63, nt = (k >> 9) & 1, sg = k >> 10;
        int q2 = sg & 1, n = sg >> 1;
        int c  = q2 * 32 + ((l >> 4) << 3) + j;
        int oc = nt * 16 + (l & 15);
        woff_frag[k] = (oc < NCH) ? f2bf(w_off[(oc * C_ + c) * 9 + n]) : (short)0;
    }
}

// ---------------- Kernel 2: fused offset-conv + deformable sample + GEMM ----------------
// Block = 256 thr (4 waves) = 4 pixel-rows x 16 cols. Each wave owns ONE pixel
// row and runs ALL 9 taps of both phases. Patch (8 rows x 24 cols x 64 ch) is
// staged DIRECTLY from NCHW f32 x with in-register bf16 conversion (no x_t
// workspace, no transpose pass). Rare |offset|>=1 lanes gather from NCHW x
// with identical RNE conversion. 2 block barriers total.
__global__ __launch_bounds__(256, 5) void deform_fused(
    const float* __restrict__ x, const short* __restrict__ woff_frag,
    const float* __restrict__ b_off, const short* __restrict__ wk_frag,
    const float* __restrict__ b_ker, float* __restrict__ out)
{
    __shared__ __align__(16) short sX[192 * PCH];   // 27648 B: [r*24+c][ch(72)]; reused as float in epilogue
    __shared__ float2 sP[4][16][9];                 // 4608 B: per-wave per-pixel (ox,oy) per tap

    int t    = threadIdx.x;
    int lane = t & 63;
    int wv   = t >> 6;                  // 0..3 = pixel row within tile
    int b    = blockIdx.x & 7;          // image -> XCD pin
    int s    = blockIdx.x >> 3;         // 0..143
    int rg   = s / 6;                   // row group: i0 = rg*4
    int cs   = s - rg * 6;              // col strip: j0 = cs*16
    int i0   = rg * 4;
    int j0   = cs * 16;
    int pxl  = lane & 15, kq = lane >> 4;
    int iw   = i0 + wv;                 // this wave's pixel row
    int j    = j0 + pxl;
    const float* xb = x + (size_t)b * C_ * HW;
    const short8 Z8 = {0,0,0,0,0,0,0,0};

    // ---- stage 8x24x64 patch directly from NCHW f32 (rows i0-2..i0+5, cols j0-4..j0+19) ----
    // unit = (cq, r, q): 4 channels x 1 row x 4 cols; 768 units, 3 per thread.
#pragma unroll
    for (int k = 0; k < 3; ++k) {
        int u   = t + k * 256;               // 0..767
        int q   = u % 6;
        int rem = u / 6;                     // 0..127
        int r   = rem & 7;
        int cq  = rem >> 3;                  // 0..15 -> channels 4cq..4cq+3
        int row = min(max(i0 - 2 + r, 0), H_ - 1);
        int c0  = j0 - 4 + q * 4;
        const float* pb = xb + (size_t)(4 * cq) * HW + row * W_;
        f32x4 v[4];
        if (c0 >= 0 && c0 <= W_ - 4) {       // aligned interior quad (16B aligned)
#pragma unroll
            for (int e = 0; e < 4; ++e) v[e] = *(const f32x4*)(pb + (size_t)e * HW + c0);
        } else {                             // border: per-col clamped scalar loads
#pragma unroll
            for (int p = 0; p < 4; ++p) {
                int cc = min(max(c0 + p, 0), W_ - 1);
#pragma unroll
                for (int e = 0; e < 4; ++e) v[e][p] = pb[(size_t)e * HW + cc];
            }
        }
        int sbase = (r * PW + q * 4) * PCH + 4 * cq;
#pragma unroll
        for (int p = 0; p < 4; ++p) {
            uint2v w;
            w[0] = pk2bf(v[0][p], v[1][p]);
            w[1] = pk2bf(v[2][p], v[3][p]);
            *(uint2v*)&sX[sbase + p * PCH] = w;
        }
    }
    __syncthreads();

    // ---- phase 1: offset conv, all 9 taps, wave-local accumulation ----
    f32x4 pa0 = {0,0,0,0}, pa1 = {0,0,0,0};
#pragma unroll
    for (int n = 0; n < 9; ++n) {
        int di = n / 3 - 1, dj = n % 3 - 1;
        bool ok = ((unsigned)(iw + di) < (unsigned)H_) & ((unsigned)(j + dj) < (unsigned)W_);
        int rcb = ((wv + di + 2) * PW + (pxl + dj + 4)) * PCH;
#pragma unroll
        for (int q2 = 0; q2 < 2; ++q2) {
            short8 a = *(const short8*)&sX[rcb + q2 * 32 + kq * 8];
            a = ok ? a : Z8;
            const short* wb = woff_frag + ((n * 2 + q2) * 2) * 512 + lane * 8;
            short8 b0 = *(const short8*)(wb);
            short8 b1 = *(const short8*)(wb + 512);
            pa0 = __builtin_amdgcn_mfma_f32_16x16x32_bf16(a, b0, pa0, 0, 0, 0);
            pa1 = __builtin_amdgcn_mfma_f32_16x16x32_bf16(a, b1, pa1, 0, 0, 0);
        }
    }
    {   // C/D: col=lane&15 (=offset ch), row=(lane>>4)*4+r (=px). Wave-local table.
        int col = lane & 15, rq = lane >> 4;
        float bo = b_off[col];
        if (col < 9) {
#pragma unroll
            for (int r = 0; r < 4; ++r) sP[wv][rq * 4 + r][col].x = pa0[r] + bo;
        } else {
#pragma unroll
            for (int r = 0; r < 4; ++r) sP[wv][rq * 4 + r][col - 9].y = pa0[r] + bo;
        }
        if (col < 2) {
            float bo2 = b_off[16 + col];
#pragma unroll
            for (int r = 0; r < 4; ++r) sP[wv][rq * 4 + r][7 + col].y = pa1[r] + bo2;
        }
    }
    // same-wave produce->consume through LDS: lgkmcnt ordering suffices, no barrier

    // ---- phase 2: sample (LDS patch, NCHW global fallback) + GEMM, all 9 taps ----
    f32x4 acc[4];
#pragma unroll
    for (int nt = 0; nt < 4; ++nt) acc[nt] = (f32x4){0.f, 0.f, 0.f, 0.f};

#pragma unroll
    for (int n = 0; n < 9; ++n) {
        int di = n / 3 - 1, dj = n % 3 - 1;
        float2 o = sP[wv][pxl][n];
        float fpx = (float)(iw + di) + o.x;
        float fpy = (float)(j + dj) + o.y;
        float x0f = floorf(fpx), y0f = floorf(fpy);
        float lx = fpx - x0f, ly = fpy - y0f;
        int xi = (int)x0f, yi = (int)y0f;
        float wx0 = (xi >= 0  && xi <= H_ - 1) ? (1.0f - lx) : 0.0f;
        float wx1 = (xi >= -1 && xi <= H_ - 2) ? lx          : 0.0f;
        float wy0 = (yi >= 0  && yi <= W_ - 1) ? (1.0f - ly) : 0.0f;
        float wy1 = (yi >= -1 && yi <= W_ - 2) ? ly          : 0.0f;
        float w00 = wx0 * wy0, w10 = wx1 * wy0, w01 = wx0 * wy1, w11 = wx1 * wy1;
        int rp = xi - (i0 - 2), cp = yi - (j0 - 4);
        bool inp = (rp >= 0) & (rp <= 6) & (cp >= 0) & (cp <= 22);
        uint4v u[8];
        if (inp) {   // common path: patch reads (content is clamp-equivalent)
            int l00 = (rp * PW + cp) * PCH;
            int l10 = l00 + PW * PCH, l01 = l00 + PCH, l11 = l10 + PCH;
#pragma unroll
            for (int q2 = 0; q2 < 2; ++q2) {
                int cho = q2 * 32 + kq * 8;
                u[q2*4+0] = *(const uint4v*)&sX[l00 + cho];
                u[q2*4+1] = *(const uint4v*)&sX[l10 + cho];
                u[q2*4+2] = *(const uint4v*)&sX[l01 + cho];
                u[q2*4+3] = *(const uint4v*)&sX[l11 + cho];
            }
        }
        if (!inp) {  // rare: |offset| >= 1 -> gather from NCHW x, same RNE convert
            int r0 = min(max(xi,     0), H_ - 1) * W_;
            int r1 = min(max(xi + 1, 0), H_ - 1) * W_;
            int c0 = min(max(yi,     0), W_ - 1);
            int c1 = min(max(yi + 1, 0), W_ - 1);
#pragma unroll
            for (int q2 = 0; q2 < 2; ++q2) {
                int cho = q2 * 32 + kq * 8;
                const float* xc = xb + (size_t)cho * HW;
#pragma unroll
                for (int d = 0; d < 4; ++d) {
                    const float* p0 = xc + (size_t)(2 * d) * HW;
                    const float* p1 = p0 + HW;
                    u[q2*4+0][d] = pk2bf(p0[r0 + c0], p1[r0 + c0]);
                    u[q2*4+1][d] = pk2bf(p0[r1 + c0], p1[r1 + c0]);
                    u[q2*4+2][d] = pk2bf(p0[r0 + c1], p1[r0 + c1]);
                    u[q2*4+3][d] = pk2bf(p0[r1 + c1], p1[r1 + c1]);
                }
            }
        }
#pragma unroll
        for (int q2 = 0; q2 < 2; ++q2) {
            short8 A;
#pragma unroll
            for (int d = 0; d < 4; ++d) {
                float lo = w00 * bflo(u[q2*4+0][d]) + w10 * bflo(u[q2*4+1][d])
                         + w01 * bflo(u[q2*4+2][d]) + w11 * bflo(u[q2*4+3][d]);
                float hi = w00 * bfhi(u[q2*4+0][d]) + w10 * bfhi(u[q2*4+1][d])
                         + w01 * bfhi(u[q2*4+2][d]) + w11 * bfhi(u[q2*4+3][d]);
                A[2 * d]     = f2bf(lo);
                A[2 * d + 1] = f2bf(hi);
            }
            const short* wbp = wk_frag + ((n * 2 + q2) * 4) * 512 + lane * 8;
#pragma unroll
            for (int nt = 0; nt < 4; ++nt) {
                short8 bfr = *(const short8*)(wbp + nt * 512);
                acc[nt] = __builtin_amdgcn_mfma_f32_16x16x32_bf16(A, bfr, acc[nt], 0, 0, 0);
            }
        }
    }

    // ---- epilogue: per-wave transpose through own LDS quarter, coalesced stores ----
    __syncthreads();                       // all waves done reading sX patch
    float* fw = (float*)sX + wv * 1280;    // 64 oc x 20 (padded) floats per wave
    {
        int col = lane & 15, rq = lane >> 4;
#pragma unroll
        for (int nt = 0; nt < 4; ++nt) {
            int oc = nt * 16 + col;
            float bias = b_ker[oc];
#pragma unroll
            for (int r = 0; r < 4; ++r)
                fw[oc * 20 + rq * 4 + r] = acc[nt][r] + bias;
        }
    }
    // wave-local write->read: no barrier needed
    {
        int ocl = lane >> 2, qq = lane & 3;
        float* ob = out + (size_t)b * OUTC * HW + iw * W_ + j0 + qq * 4;
#pragma unroll
        for (int it = 0; it < 4; ++it) {
            int oc = it * 16 + ocl;
            f32x4 v = *(const f32x4*)&fw[oc * 20 + qq * 4];
            *(f32x4*)(ob + (size_t)oc * HW) = v;
        }
    }
}

extern "C" void kernel_launch(void* const* d_in, const int* in_sizes, int n_in,
                              void* d_out, int out_size, void* d_ws, size_t ws_size,
                              hipStream_t stream) {
    const float* x     = (const float*)d_in[0];
    const float* w_off = (const float*)d_in[1];
    const float* b_off = (const float*)d_in[2];
    const float* w_ker = (const float*)d_in[3];
    const float* b_ker = (const float*)d_in[4];
    float* out = (float*)d_out;

    // workspace: wk_frag 73,728 B | woff_frag 36,864 B
    char*  wsb       = (char*)d_ws;
    short* wk_frag   = (short*)wsb;
    short* woff_frag = wk_frag + 36864;

    prep_w      <<<216,  256, 0, stream>>>(w_ker, w_off, wk_frag, woff_frag);
    deform_fused<<<1152, 256, 0, stream>>>(x, woff_frag, b_off, wk_frag, b_ker, out);
}